// Round 1
// baseline (3936.419 us; speedup 1.0000x reference)
//
#include <hip/hip_runtime.h>
#include <math.h>

#define H 256
#define FOURH 1024
#define NV 10000
#define B 512
#define L 256
#define E 64

// ws layout (float offsets)
#define OFF_WIHT   0          // [256][1024]  WihT[k*1024+r] = W_ih[r*256+k]
#define OFF_WHHT   262144     // [256][1024]
#define OFF_WA1HT  524288     // [256][256]   Wa1hT[k*256+j] = Wa1[j*512+k]
#define OFF_WA1NT  589824     // [256][256]   Wa1nT[k*256+j] = Wa1[j*512+256+k]
#define OFF_WC1T   655360     // [256][256]
#define OFF_PEMB   720896     // [10000][1024]  graph_emb @ W_ih^T + (b_ih+b_hh)
#define OFF_AEMB   10960896   // [10000][256]   graph_emb @ Wa1n^T
#define OFF_HBUF   13520896   // [512][256]     h_final
// total = 13,651,968 floats = 54.6 MB of ws

__global__ __launch_bounds__(256) void k_prep(
    const float* __restrict__ W_ih, const float* __restrict__ W_hh,
    const float* __restrict__ Wa1, const float* __restrict__ Wc1,
    float* __restrict__ ws) {
  int idx = blockIdx.x * 256 + threadIdx.x;
  if (idx < 262144) {
    int k = idx >> 10, r = idx & 1023;
    ws[OFF_WIHT + idx] = W_ih[r * 256 + k];
    ws[OFF_WHHT + idx] = W_hh[r * 256 + k];
  }
  int i2 = idx - 262144;
  if (i2 >= 0 && i2 < 65536) {
    int k = i2 >> 8, j = i2 & 255;
    ws[OFF_WA1HT + i2] = Wa1[j * 512 + k];
    ws[OFF_WA1NT + i2] = Wa1[j * 512 + 256 + k];
    ws[OFF_WC1T + i2] = Wc1[j * 256 + k];
  }
}

// P_emb[v][col] = sum_k graph_emb[v,k]*W_ih[col,k] + b_ih[col]+b_hh[col]
__global__ __launch_bounds__(1024) void k_pemb(
    const float* __restrict__ ge, const float* __restrict__ b_ih,
    const float* __restrict__ b_hh, float* __restrict__ ws) {
  __shared__ float X[16][256];
  const float* __restrict__ WihT = ws + OFF_WIHT;
  float* __restrict__ P = ws + OFF_PEMB;
  const int vbase = blockIdx.x * 16;
  const int tid = threadIdx.x;
  for (int i = tid; i < 16 * 256; i += 1024)
    X[i >> 8][i & 255] = ge[(vbase + (i >> 8)) * 256 + (i & 255)];
  __syncthreads();
  float acc[16];
#pragma unroll
  for (int v = 0; v < 16; ++v) acc[v] = 0.f;
  const int col = tid;
  for (int k = 0; k < 256; ++k) {
    float w = WihT[k * 1024 + col];
#pragma unroll
    for (int v = 0; v < 16; ++v) acc[v] += w * X[v][k];
  }
  const float bias = b_ih[col] + b_hh[col];
#pragma unroll
  for (int v = 0; v < 16; ++v)
    P[(size_t)(vbase + v) * 1024 + col] = acc[v] + bias;
}

// A_emb[v][j] = sum_k graph_emb[v,k]*Wa1[j,256+k]
__global__ __launch_bounds__(256) void k_aemb(
    const float* __restrict__ ge, float* __restrict__ ws) {
  __shared__ float X[16][256];
  const float* __restrict__ WnT = ws + OFF_WA1NT;
  float* __restrict__ A = ws + OFF_AEMB;
  const int vbase = blockIdx.x * 16;
  const int tid = threadIdx.x;
  for (int i = tid; i < 16 * 256; i += 256)
    X[i >> 8][i & 255] = ge[(vbase + (i >> 8)) * 256 + (i & 255)];
  __syncthreads();
  float acc[16];
#pragma unroll
  for (int v = 0; v < 16; ++v) acc[v] = 0.f;
  for (int k = 0; k < 256; ++k) {
    float w = WnT[k * 256 + tid];
#pragma unroll
    for (int v = 0; v < 16; ++v) acc[v] += w * X[v][k];
  }
#pragma unroll
  for (int v = 0; v < 16; ++v)
    A[(size_t)(vbase + v) * 256 + tid] = acc[v];
}

// One workgroup per path: LSTM recurrence + fused critic head.
__global__ __launch_bounds__(256) void k_lstm(
    const int* __restrict__ paths, const int* __restrict__ path_lens,
    const float* __restrict__ bc1, const float* __restrict__ Wc2,
    const float* __restrict__ bc2, float* __restrict__ out,
    float* __restrict__ ws) {
  __shared__ float h[256];
  __shared__ float c[256];
  __shared__ float g4[1024];
  const float* __restrict__ WhhT = ws + OFF_WHHT;
  const float* __restrict__ P = ws + OFF_PEMB;
  const float* __restrict__ Wc1T = ws + OFF_WC1T;
  float* __restrict__ hbuf = ws + OFF_HBUF;
  const int b = blockIdx.x;
  const int j = threadIdx.x;
  h[j] = 0.f;
  c[j] = 0.f;
  __syncthreads();
  const int len = path_lens[b];
  const float4* __restrict__ wp = (const float4*)(WhhT + 4 * j);
  for (int t = 0; t < len; ++t) {
    const int v = paths[b * L + t];
    float4 acc = *(const float4*)(P + (size_t)v * 1024 + 4 * j);
#pragma unroll 4
    for (int k = 0; k < 256; ++k) {
      const float hk = h[k];
      const float4 w = wp[k * 256];  // row k of WhhT, cols 4j..4j+3
      acc.x += w.x * hk;
      acc.y += w.y * hk;
      acc.z += w.z * hk;
      acc.w += w.w * hk;
    }
    *(float4*)(g4 + 4 * j) = acc;
    __syncthreads();
    // gate order i,f,g,o
    const float gi = g4[j], gf = g4[j + 256], gg = g4[j + 512], go = g4[j + 768];
    const float si = 1.f / (1.f + expf(-gi));
    const float sf = 1.f / (1.f + expf(-gf));
    const float so = 1.f / (1.f + expf(-go));
    const float cn = sf * c[j] + si * tanhf(gg);
    const float hn = so * tanhf(cn);
    c[j] = cn;
    h[j] = hn;  // safe: all k-loop reads of h happened before prior barrier
    __syncthreads();
  }
  hbuf[b * 256 + j] = h[j];
  // critic: value = Wc2 @ elu(Wc1 @ h + bc1) + bc2
  float ch = bc1[j];
  for (int k = 0; k < 256; ++k) ch += Wc1T[k * 256 + j] * h[k];
  ch = ch > 0.f ? ch : expm1f(ch);
  g4[j] = ch * Wc2[j];
  __syncthreads();
  for (int s = 128; s > 0; s >>= 1) {
    if (j < s) g4[j] += g4[j + s];
    __syncthreads();
  }
  if (j == 0) out[B * E + b] = g4[0] + bc2[0];
}

// One workgroup per path: actor head + masked softmax.
__global__ __launch_bounds__(256) void k_actor(
    const int* __restrict__ neighbors, const int* __restrict__ n_nb,
    const float* __restrict__ ba1, const float* __restrict__ Wa2,
    const float* __restrict__ ba2, float* __restrict__ out,
    const float* __restrict__ ws) {
  __shared__ float hs[256];
  __shared__ float u[256];
  __shared__ float logits[64];
  const float* __restrict__ Wa1hT = ws + OFF_WA1HT;
  const float* __restrict__ A = ws + OFF_AEMB;
  const float* __restrict__ hbuf = ws + OFF_HBUF;
  const int b = blockIdx.x;
  const int j = threadIdx.x;
  hs[j] = hbuf[b * 256 + j];
  __syncthreads();
  float acc = ba1[j];
  for (int k = 0; k < 256; ++k) acc += Wa1hT[k * 256 + j] * hs[k];
  u[j] = acc;
  __syncthreads();
  const int wave = j >> 6, lane = j & 63;
  const float ba2v = ba2[0];
  for (int e = wave; e < 64; e += 4) {
    const int v = neighbors[b * 64 + e];
    float s = 0.f;
#pragma unroll
    for (int m = 0; m < 4; ++m) {
      const int jj = lane + 64 * m;
      float a = u[jj] + A[(size_t)v * 256 + jj];
      a = a > 0.f ? a : expm1f(a);
      s += a * Wa2[jj];
    }
#pragma unroll
    for (int d = 32; d > 0; d >>= 1) s += __shfl_xor(s, d, 64);
    if (lane == 0) logits[e] = s + ba2v;
  }
  __syncthreads();
  if (j < 64) {
    const int ne = n_nb[b];
    const bool valid = j < ne;
    float le = valid ? logits[j] : -1e30f;
    float m = le;
#pragma unroll
    for (int d = 32; d > 0; d >>= 1) m = fmaxf(m, __shfl_xor(m, d, 64));
    float p = valid ? expf(le - m) : 0.f;
    float sm = p;
#pragma unroll
    for (int d = 32; d > 0; d >>= 1) sm += __shfl_xor(sm, d, 64);
    out[b * 64 + j] = p / sm;
  }
}

extern "C" void kernel_launch(void* const* d_in, const int* in_sizes, int n_in,
                              void* d_out, int out_size, void* d_ws, size_t ws_size,
                              hipStream_t stream) {
  (void)in_sizes; (void)n_in; (void)out_size; (void)ws_size;
  const float* graph_emb = (const float*)d_in[0];
  const int* paths       = (const int*)d_in[1];
  const int* path_lens   = (const int*)d_in[2];
  const int* neighbors   = (const int*)d_in[3];
  const int* n_nb        = (const int*)d_in[4];
  const float* W_ih = (const float*)d_in[5];
  const float* W_hh = (const float*)d_in[6];
  const float* b_ih = (const float*)d_in[7];
  const float* b_hh = (const float*)d_in[8];
  const float* Wa1  = (const float*)d_in[9];
  const float* ba1  = (const float*)d_in[10];
  const float* Wa2  = (const float*)d_in[11];
  const float* ba2  = (const float*)d_in[12];
  const float* Wc1  = (const float*)d_in[13];
  const float* bc1  = (const float*)d_in[14];
  const float* Wc2  = (const float*)d_in[15];
  const float* bc2  = (const float*)d_in[16];
  float* out = (float*)d_out;
  float* ws = (float*)d_ws;

  hipLaunchKernelGGL(k_prep, dim3(1280), dim3(256), 0, stream, W_ih, W_hh, Wa1, Wc1, ws);
  hipLaunchKernelGGL(k_pemb, dim3(625), dim3(1024), 0, stream, graph_emb, b_ih, b_hh, ws);
  hipLaunchKernelGGL(k_aemb, dim3(625), dim3(256), 0, stream, graph_emb, ws);
  hipLaunchKernelGGL(k_lstm, dim3(512), dim3(256), 0, stream, paths, path_lens, bc1, Wc2, bc2, out, ws);
  hipLaunchKernelGGL(k_actor, dim3(512), dim3(256), 0, stream, neighbors, n_nb, ba1, Wa2, ba2, out, ws);
}

// Round 2
// 2746.716 us; speedup vs baseline: 1.4331x; 1.4331x over previous
//
#include <hip/hip_runtime.h>
#include <math.h>

#define H 256
#define FOURH 1024
#define NV 10000
#define B 512
#define L 256
#define E 64

// ws layout (float offsets)
#define OFF_WIHT   0          // [256][1024] fp32: WihT[k*1024+r] = W_ih[r*256+k]
#define OFF_WHH2   262144     // [128][1024] uint32: packed bf16 pair (k=2k2 lo, 2k2+1 hi), col r
#define OFF_WA1HT  393216     // [256][256]  Wa1hT[k*256+j] = Wa1[j*512+k]
#define OFF_WA1NT  458752     // [256][256]  Wa1nT[k*256+j] = Wa1[j*512+256+k]
#define OFF_WC1T   524288     // [256][256]
#define OFF_PEMB   589824     // [10000][1024] fp32: graph_emb @ W_ih^T + (b_ih+b_hh)
#define OFF_AEMB   10829824   // [10000][256]  fp32: graph_emb @ Wa1n^T
#define OFF_HBUF   13389824   // [512][256]    h_final
// total = 13,520,896 floats = 54.08 MB of ws

__device__ inline unsigned int f2bf(float f) {
  unsigned int u = __float_as_uint(f);
  u += 0x7FFFu + ((u >> 16) & 1u);  // round-to-nearest-even
  return u >> 16;
}

__global__ __launch_bounds__(256) void k_prep(
    const float* __restrict__ W_ih, const float* __restrict__ W_hh,
    const float* __restrict__ Wa1, const float* __restrict__ Wc1,
    float* __restrict__ ws) {
  int idx = blockIdx.x * 256 + threadIdx.x;
  if (idx < 262144) {
    int k = idx >> 10, r = idx & 1023;
    ws[OFF_WIHT + idx] = W_ih[r * 256 + k];
    return;
  }
  int p = idx - 262144;
  if (p < 131072) {  // packed bf16 W_hh^T pairs
    int k2 = p >> 10, r = p & 1023;
    unsigned int lo = f2bf(W_hh[r * 256 + 2 * k2]);
    unsigned int hi = f2bf(W_hh[r * 256 + 2 * k2 + 1]);
    ((unsigned int*)ws)[OFF_WHH2 + (size_t)k2 * 1024 + r] = (hi << 16) | lo;
    return;
  }
  int i2 = p - 131072;
  if (i2 < 65536) {
    int k = i2 >> 8, j = i2 & 255;
    ws[OFF_WA1HT + i2] = Wa1[j * 512 + k];
    ws[OFF_WA1NT + i2] = Wa1[j * 512 + 256 + k];
    ws[OFF_WC1T + i2] = Wc1[j * 256 + k];
  }
}

// P_emb[v][col] = sum_k graph_emb[v,k]*W_ih[col,k] + b_ih[col]+b_hh[col]
__global__ __launch_bounds__(1024) void k_pemb(
    const float* __restrict__ ge, const float* __restrict__ b_ih,
    const float* __restrict__ b_hh, float* __restrict__ ws) {
  __shared__ float X[16][256];
  const float* __restrict__ WihT = ws + OFF_WIHT;
  float* __restrict__ P = ws + OFF_PEMB;
  const int vbase = blockIdx.x * 16;
  const int tid = threadIdx.x;
  for (int i = tid; i < 16 * 256; i += 1024)
    X[i >> 8][i & 255] = ge[(vbase + (i >> 8)) * 256 + (i & 255)];
  __syncthreads();
  float acc[16];
#pragma unroll
  for (int v = 0; v < 16; ++v) acc[v] = 0.f;
  const int col = tid;
  for (int k = 0; k < 256; ++k) {
    float w = WihT[k * 1024 + col];
#pragma unroll
    for (int v = 0; v < 16; ++v) acc[v] += w * X[v][k];
  }
  const float bias = b_ih[col] + b_hh[col];
#pragma unroll
  for (int v = 0; v < 16; ++v)
    P[(size_t)(vbase + v) * 1024 + col] = acc[v] + bias;
}

// A_emb[v][j] = sum_k graph_emb[v,k]*Wa1[j,256+k]
__global__ __launch_bounds__(256) void k_aemb(
    const float* __restrict__ ge, float* __restrict__ ws) {
  __shared__ float X[16][256];
  const float* __restrict__ WnT = ws + OFF_WA1NT;
  float* __restrict__ A = ws + OFF_AEMB;
  const int vbase = blockIdx.x * 16;
  const int tid = threadIdx.x;
  for (int i = tid; i < 16 * 256; i += 256)
    X[i >> 8][i & 255] = ge[(vbase + (i >> 8)) * 256 + (i & 255)];
  __syncthreads();
  float acc[16];
#pragma unroll
  for (int v = 0; v < 16; ++v) acc[v] = 0.f;
  for (int k = 0; k < 256; ++k) {
    float w = WnT[k * 256 + tid];
#pragma unroll
    for (int v = 0; v < 16; ++v) acc[v] += w * X[v][k];
  }
#pragma unroll
  for (int v = 0; v < 16; ++v)
    A[(size_t)(vbase + v) * 256 + tid] = acc[v];
}

// One workgroup per path: LSTM recurrence (bf16 weights) + fused critic head.
__global__ __launch_bounds__(256) void k_lstm(
    const int* __restrict__ paths, const int* __restrict__ path_lens,
    const float* __restrict__ bc1, const float* __restrict__ Wc2,
    const float* __restrict__ bc2, float* __restrict__ out,
    float* __restrict__ ws) {
  __shared__ float hsm[256];
  __shared__ float g4[1024];
  const uint4* __restrict__ W2 = (const uint4*)((const unsigned int*)ws + OFF_WHH2);
  const float* __restrict__ P = ws + OFF_PEMB;
  const float* __restrict__ Wc1T = ws + OFF_WC1T;
  float* __restrict__ hbuf = ws + OFF_HBUF;
  const int b = blockIdx.x;
  const int j = threadIdx.x;
  hsm[j] = 0.f;
  float c_reg = 0.f;  // thread j owns c[j]
  __syncthreads();
  const int len = path_lens[b];
  const uint4* __restrict__ wp = W2 + j;  // row k2, uint4 index k2*256 + j
  for (int t = 0; t < len; ++t) {
    const int v = paths[b * L + t];
    float4 acc = *(const float4*)(P + (size_t)v * 1024 + 4 * j);
#pragma unroll 8
    for (int k2 = 0; k2 < 128; ++k2) {
      const uint4 w = wp[k2 * 256];  // 8 bf16: cols 4j..4j+3 x k={2k2,2k2+1}
      const float2 hv = *(const float2*)(hsm + 2 * k2);
      acc.x += __uint_as_float(w.x << 16) * hv.x + __uint_as_float(w.x & 0xFFFF0000u) * hv.y;
      acc.y += __uint_as_float(w.y << 16) * hv.x + __uint_as_float(w.y & 0xFFFF0000u) * hv.y;
      acc.z += __uint_as_float(w.z << 16) * hv.x + __uint_as_float(w.z & 0xFFFF0000u) * hv.y;
      acc.w += __uint_as_float(w.w << 16) * hv.x + __uint_as_float(w.w & 0xFFFF0000u) * hv.y;
    }
    *(float4*)(g4 + 4 * j) = acc;
    __syncthreads();
    // gate order i,f,g,o
    const float gi = g4[j], gf = g4[j + 256], gg = g4[j + 512], go = g4[j + 768];
    const float si = 1.f / (1.f + expf(-gi));
    const float sf = 1.f / (1.f + expf(-gf));
    const float so = 1.f / (1.f + expf(-go));
    c_reg = sf * c_reg + si * tanhf(gg);
    hsm[j] = so * tanhf(c_reg);  // safe: all k-loop reads of old h preceded barrier above
    __syncthreads();
  }
  const float hj = hsm[j];
  hbuf[b * 256 + j] = hj;
  // critic: value = Wc2 @ elu(Wc1 @ h + bc1) + bc2
  float ch = bc1[j];
  for (int k = 0; k < 256; ++k) ch += Wc1T[k * 256 + j] * hsm[k];
  ch = ch > 0.f ? ch : expm1f(ch);
  g4[j] = ch * Wc2[j];
  __syncthreads();
  for (int s = 128; s > 0; s >>= 1) {
    if (j < s) g4[j] += g4[j + s];
    __syncthreads();
  }
  if (j == 0) out[B * E + b] = g4[0] + bc2[0];
}

// One workgroup per path: actor head + masked softmax.
__global__ __launch_bounds__(256) void k_actor(
    const int* __restrict__ neighbors, const int* __restrict__ n_nb,
    const float* __restrict__ ba1, const float* __restrict__ Wa2,
    const float* __restrict__ ba2, float* __restrict__ out,
    const float* __restrict__ ws) {
  __shared__ float hs[256];
  __shared__ float u[256];
  __shared__ float logits[64];
  const float* __restrict__ Wa1hT = ws + OFF_WA1HT;
  const float* __restrict__ A = ws + OFF_AEMB;
  const float* __restrict__ hbuf = ws + OFF_HBUF;
  const int b = blockIdx.x;
  const int j = threadIdx.x;
  hs[j] = hbuf[b * 256 + j];
  __syncthreads();
  float acc = ba1[j];
  for (int k = 0; k < 256; ++k) acc += Wa1hT[k * 256 + j] * hs[k];
  u[j] = acc;
  __syncthreads();
  const int wave = j >> 6, lane = j & 63;
  const float ba2v = ba2[0];
  for (int e = wave; e < 64; e += 4) {
    const int v = neighbors[b * 64 + e];
    float s = 0.f;
#pragma unroll
    for (int m = 0; m < 4; ++m) {
      const int jj = lane + 64 * m;
      float a = u[jj] + A[(size_t)v * 256 + jj];
      a = a > 0.f ? a : expm1f(a);
      s += a * Wa2[jj];
    }
#pragma unroll
    for (int d = 32; d > 0; d >>= 1) s += __shfl_xor(s, d, 64);
    if (lane == 0) logits[e] = s + ba2v;
  }
  __syncthreads();
  if (j < 64) {
    const int ne = n_nb[b];
    const bool valid = j < ne;
    float le = valid ? logits[j] : -1e30f;
    float m = le;
#pragma unroll
    for (int d = 32; d > 0; d >>= 1) m = fmaxf(m, __shfl_xor(m, d, 64));
    float p = valid ? expf(le - m) : 0.f;
    float sm = p;
#pragma unroll
    for (int d = 32; d > 0; d >>= 1) sm += __shfl_xor(sm, d, 64);
    out[b * 64 + j] = p / sm;
  }
}

extern "C" void kernel_launch(void* const* d_in, const int* in_sizes, int n_in,
                              void* d_out, int out_size, void* d_ws, size_t ws_size,
                              hipStream_t stream) {
  (void)in_sizes; (void)n_in; (void)out_size; (void)ws_size;
  const float* graph_emb = (const float*)d_in[0];
  const int* paths       = (const int*)d_in[1];
  const int* path_lens   = (const int*)d_in[2];
  const int* neighbors   = (const int*)d_in[3];
  const int* n_nb        = (const int*)d_in[4];
  const float* W_ih = (const float*)d_in[5];
  const float* W_hh = (const float*)d_in[6];
  const float* b_ih = (const float*)d_in[7];
  const float* b_hh = (const float*)d_in[8];
  const float* Wa1  = (const float*)d_in[9];
  const float* ba1  = (const float*)d_in[10];
  const float* Wa2  = (const float*)d_in[11];
  const float* ba2  = (const float*)d_in[12];
  const float* Wc1  = (const float*)d_in[13];
  const float* bc1  = (const float*)d_in[14];
  const float* Wc2  = (const float*)d_in[15];
  const float* bc2  = (const float*)d_in[16];
  float* out = (float*)d_out;
  float* ws = (float*)d_ws;

  hipLaunchKernelGGL(k_prep, dim3(1792), dim3(256), 0, stream, W_ih, W_hh, Wa1, Wc1, ws);
  hipLaunchKernelGGL(k_pemb, dim3(625), dim3(1024), 0, stream, graph_emb, b_ih, b_hh, ws);
  hipLaunchKernelGGL(k_aemb, dim3(625), dim3(256), 0, stream, graph_emb, ws);
  hipLaunchKernelGGL(k_lstm, dim3(512), dim3(256), 0, stream, paths, path_lens, bc1, Wc2, bc2, out, ws);
  hipLaunchKernelGGL(k_actor, dim3(512), dim3(256), 0, stream, neighbors, n_nb, ba1, Wa2, ba2, out, ws);
}